// Round 12
// baseline (4439.647 us; speedup 1.0000x reference)
//
#include <hip/hip_runtime.h>

// QINCo round 12: m/h wave decomposition — H lives in registers.
// Wave (mb,hh): m-tile mb (32 m), h-half hh (128 h of 256).
//  GEMM1: A=W1[h][d] (global pre-split), B=Z[m-tile] (LDS): 2 ds_read_b128
//          feed 12 MFMA (4 h-tile chains). C = H^T[h][m] in registers.
//  Convert: C-layout -> B-layout via __shfl_xor(32) (cross-koct quad swap),
//          relu + rescale + hi/lo split, all in registers.
//  GEMM2: A=W2[d][h] (global pre-split), B=H regs: zero LDS reads. Partial
//          C[128 d][32 m] over own h-half; hh-pair reduces via 32KB LDS X-buf,
//          each wave updates its d-half of Z. 2 barriers/layer (R10: 4).
// LDS: Zh|Zl (32KB) + X (32KB) = 64KB. Pre-split fp16 hi/lo weights.
// Shapes: D=128, M=8, K=256, L=2, H=256, BS=1024.
// Out layout (floats): xhat[1024*128] | codes[1024*8] | side[8][1024*128]

typedef _Float16 f16;
typedef f16 half4_t __attribute__((ext_vector_type(4)));
typedef f16 half8_t __attribute__((ext_vector_type(8)));
typedef float f32x16 __attribute__((ext_vector_type(16)));

#define OUT_CODES 131072
#define OUT_SIDE  139264

// ws float offsets
#define WS_XHAT  0          // [1024][128]
#define WS_RB    131072     // [1024][128]  r = x - xhat
#define WS_Y     262144     // [1024][128]  y = xhat @ Wx^T
#define WS_ZC    393216     // [256][128]   zc = cb + cb@Wz^T + bc
#define WS_BESTD 425984     // [1024][4]
#define WS_BESTI 430080     // [1024][4] (int)
#define WS_BESTZ 434176     // [1024][4][128]
#define WS_WSPLIT 960000    // f16 region: W1H|W1L|W2H|W2L, NW1 halfs each
#define NW1 458752          // 7*2*256*128

#define ZLO 8192            // Zh -> Zl offset in halfs (same LDS array)

__device__ __forceinline__ f32x16 mfma_f16(half8_t a, half8_t b, f32x16 c) {
  return __builtin_amdgcn_mfma_f32_32x32x16_f16(a, b, c, 0, 0, 0);
}

// ---------------- weight pre-split: fp32 -> scaled (x256) fp16 hi/lo ----------------
__global__ __launch_bounds__(256) void k_wsplit(const float* __restrict__ W1,
    const float* __restrict__ W2, f16* __restrict__ wsh)
{
  int i = (blockIdx.x * 256 + threadIdx.x) * 4;      // [0, 2*NW1)
  const float* src;
  f16* hi;
  if (i < NW1) { src = W1 + i; hi = wsh + i; }
  else         { src = W2 + (i - NW1); hi = wsh + 2 * NW1 + (i - NW1); }
  f16* lo = hi + NW1;
  float4 v = *(const float4*)src;
  half4_t h, l;
  float s;
  s = v.x * 256.f; h[0] = (f16)s; l[0] = (f16)(s - (float)h[0]);
  s = v.y * 256.f; h[1] = (f16)s; l[1] = (f16)(s - (float)h[1]);
  s = v.z * 256.f; h[2] = (f16)s; l[2] = (f16)(s - (float)h[2]);
  s = v.w * 256.f; h[3] = (f16)s; l[3] = (f16)(s - (float)h[3]);
  *(half4_t*)hi = h;
  *(half4_t*)lo = l;
}

// ---------------- step 0: nearest codebook0 row ----------------
__global__ __launch_bounds__(256) void k_step0(const float* __restrict__ x,
    const float* __restrict__ cb0, float* __restrict__ ws, float* __restrict__ out)
{
  __shared__ float xs[128];
  __shared__ float redv[4];
  __shared__ int   redi[4];
  __shared__ int   kwin;
  int tx = threadIdx.x, b = blockIdx.x;
  if (tx < 128) xs[tx] = x[b * 128 + tx];
  __syncthreads();
  const float* c = cb0 + tx * 128;   // k = tx
  float s = 0.f;
  for (int d = 0; d < 128; d += 4) {
    float4 cv = *(const float4*)(c + d);
    float4 xv = *(const float4*)(xs + d);
    float a0 = xv.x - cv.x, a1 = xv.y - cv.y, a2 = xv.z - cv.z, a3 = xv.w - cv.w;
    s += a0 * a0 + a1 * a1 + a2 * a2 + a3 * a3;
  }
  float v = s; int idx = tx;
  for (int off = 32; off; off >>= 1) {
    float v2 = __shfl_xor(v, off);
    int   i2 = __shfl_xor(idx, off);
    if (v2 < v || (v2 == v && i2 < idx)) { v = v2; idx = i2; }
  }
  if ((tx & 63) == 0) { redv[tx >> 6] = v; redi[tx >> 6] = idx; }
  __syncthreads();
  if (tx == 0) {
    float bv = redv[0]; int bi = redi[0];
    for (int w = 1; w < 4; w++)
      if (redv[w] < bv || (redv[w] == bv && redi[w] < bi)) { bv = redv[w]; bi = redi[w]; }
    kwin = bi;
    out[OUT_CODES + b * 8] = (float)bi;
  }
  __syncthreads();
  int k = kwin;
  if (tx < 128) {
    float xh = cb0[k * 128 + tx];
    ws[WS_XHAT + b * 128 + tx] = xh;
    ws[WS_RB   + b * 128 + tx] = xs[tx] - xh;
    out[OUT_SIDE + b * 128 + tx] = xh;   // side[0]
  }
}

// ---------------- per-step prep: zc and y (fp32) ----------------
__global__ __launch_bounds__(128) void k_prep(const float* __restrict__ cb,
    const float* __restrict__ Wc, const float* __restrict__ bcm, float* __restrict__ ws)
{
  __shared__ float row[128];
  int tx = threadIdx.x, blk = blockIdx.x;
  if (blk < 256) {          // zc[k][i] = cb[k][i] + sum_d cb[k][d]*Wc[i][d] + bc[i]
    row[tx] = cb[blk * 128 + tx];
    __syncthreads();
    const float* wrow = Wc + tx * 256;
    float s = 0.f;
    for (int d = 0; d < 128; d += 4) {
      float4 wv = *(const float4*)(wrow + d);
      float4 zv = *(const float4*)(row + d);
      s += wv.x * zv.x + wv.y * zv.y + wv.z * zv.z + wv.w * zv.w;
    }
    ws[WS_ZC + blk * 128 + tx] = row[tx] + s + bcm[tx];
  } else {                  // y[b][i] = sum_d xhat[b][d]*Wc[i][128+d]
    int b = blk - 256;
    row[tx] = ws[WS_XHAT + b * 128 + tx];
    __syncthreads();
    const float* wrow = Wc + tx * 256 + 128;
    float s = 0.f;
    for (int d = 0; d < 128; d += 4) {
      float4 wv = *(const float4*)(wrow + d);
      float4 zv = *(const float4*)(row + d);
      s += wv.x * zv.x + wv.y * zv.y + wv.z * zv.z + wv.w * zv.w;
    }
    ws[WS_Y + b * 128 + tx] = s;
  }
}

// ---------------- main step kernel ----------------
// 256 threads = 4 waves; wave w: mb = w&1, hh = w>>1.
// lane: col = lane&31, koct = lane>>5.
// Z LDS: [64 m][128 d] halfs, logical d at phys (d + 8*(m&15)) & 127.
// C/D layout (32x32x16): col = n, row = (reg&3) + 8*(reg>>2) + 4*koct.
__global__ __launch_bounds__(256, 2) void k_step(const f16* __restrict__ wsh,
    float* __restrict__ ws, int sm)
{
  __shared__ __align__(16) f16 lds[32768];     // 64 KB: Zh|Zl (32K) + X (32K)
  f16* Zh = lds;
  float* Xbuf = (float*)(lds + 16384);         // 8192 floats
  int tx = threadIdx.x;
  int lane = tx & 63, w = tx >> 6;
  int col = lane & 31, koct = lane >> 5;
  int mb = w & 1, hh = w >> 1;
  int b = blockIdx.x >> 2, t = blockIdx.x & 3, k0 = t << 6;

  // ---- init Z = zc[k0+m] + y[b], split x256 into Zh/Zl (rotated store) ----
  {
    const float* zc = ws + WS_ZC + k0 * 128;
    const float* y  = ws + WS_Y + b * 128;
    for (int idx = tx; idx < 1024; idx += 256) {
      int m = idx & 63, d0 = (idx >> 6) << 3;
      float4 a  = *(const float4*)(zc + m * 128 + d0);
      float4 bb = *(const float4*)(zc + m * 128 + d0 + 4);
      float4 ya = *(const float4*)(y + d0);
      float4 yb = *(const float4*)(y + d0 + 4);
      float sv[8] = {a.x + ya.x, a.y + ya.y, a.z + ya.z, a.w + ya.w,
                     bb.x + yb.x, bb.y + yb.y, bb.z + yb.z, bb.w + yb.w};
      half8_t h8, l8;
#pragma unroll
      for (int j = 0; j < 8; j++) {
        float v = sv[j] * 256.f;
        f16 h = (f16)v; h8[j] = h; l8[j] = (f16)(v - (float)h);
      }
      int c0 = (d0 + ((m & 15) << 3)) & 127;
      *(half8_t*)(Zh + (m << 7) + c0) = h8;
      *(half8_t*)(Zh + ZLO + (m << 7) + c0) = l8;
    }
  }
  __syncthreads();

  const int mrow = (mb << 5) + col;
  const int rot0 = (col & 15) << 3;
  const f16* Zr = Zh + (mrow << 7);

  for (int l = 0; l < 2; l++) {
    const f16* w1h = wsh + (size_t)((sm * 2 + l) * 256) * 128;
    const f16* w2h = wsh + 2 * NW1 + (size_t)((sm * 2 + l) * 128) * 256;
    const f16* a1p = w1h + (size_t)((hh << 7) + col) * 128 + (koct << 3);
    const f16* a2p = w2h + (size_t)col * 256 + (hh << 7) + (koct << 3);

    // ---- GEMM1: acc1[ht] = H^T[h=128hh+32ht+row][m-tile mb] ----
    f32x16 acc1[4];
#pragma unroll
    for (int i = 0; i < 16; i++) { acc1[0][i] = 0.f; acc1[1][i] = 0.f;
                                   acc1[2][i] = 0.f; acc1[3][i] = 0.f; }
#pragma unroll
    for (int kc = 0; kc < 8; kc++) {
      int poff = (((kc << 4) + (koct << 3)) + rot0) & 127;
      half8_t bh = *(const half8_t*)(Zr + poff);
      half8_t bl = *(const half8_t*)(Zr + ZLO + poff);
      const f16* a1b = a1p + (kc << 4);
      half8_t ah[4], al[4];
#pragma unroll
      for (int ht = 0; ht < 4; ht++) {
        ah[ht] = *(const half8_t*)(a1b + ht * 4096);
        al[ht] = *(const half8_t*)(a1b + NW1 + ht * 4096);
      }
#pragma unroll
      for (int ht = 0; ht < 4; ht++) acc1[ht] = mfma_f16(ah[ht], bh, acc1[ht]);
#pragma unroll
      for (int ht = 0; ht < 4; ht++) acc1[ht] = mfma_f16(al[ht], bh, acc1[ht]);
#pragma unroll
      for (int ht = 0; ht < 4; ht++) acc1[ht] = mfma_f16(ah[ht], bl, acc1[ht]);
    }

    // ---- convert C-layout -> GEMM2 B-fragments (registers only) ----
    // kb = 2*ht + sub covers h_local 16*kb..+16 of this wave's 128 h.
    half8_t bfh[8], bfl[8];
#pragma unroll
    for (int ht = 0; ht < 4; ht++) {
#pragma unroll
      for (int sub = 0; sub < 2; sub++) {
        int rbase = sub << 3;
        float r0 = __shfl_xor(koct ? acc1[ht][rbase + 0] : acc1[ht][rbase + 4], 32);
        float r1 = __shfl_xor(koct ? acc1[ht][rbase + 1] : acc1[ht][rbase + 5], 32);
        float r2 = __shfl_xor(koct ? acc1[ht][rbase + 2] : acc1[ht][rbase + 6], 32);
        float r3 = __shfl_xor(koct ? acc1[ht][rbase + 3] : acc1[ht][rbase + 7], 32);
        float v[8];
        v[0] = koct ? r0 : acc1[ht][rbase + 0];
        v[1] = koct ? r1 : acc1[ht][rbase + 1];
        v[2] = koct ? r2 : acc1[ht][rbase + 2];
        v[3] = koct ? r3 : acc1[ht][rbase + 3];
        v[4] = koct ? acc1[ht][rbase + 4] : r0;
        v[5] = koct ? acc1[ht][rbase + 5] : r1;
        v[6] = koct ? acc1[ht][rbase + 6] : r2;
        v[7] = koct ? acc1[ht][rbase + 7] : r3;
        int kb = (ht << 1) + sub;
        half8_t hv, lv;
#pragma unroll
        for (int j = 0; j < 8; j++) {
          float tv = fmaxf(v[j], 0.f) * 0.00390625f;   // acc*2^-16 * 2^8
          f16 h = (f16)tv; hv[j] = h; lv[j] = (f16)(tv - (float)h);
        }
        bfh[kb] = hv; bfl[kb] = lv;
      }
    }

    // ---- GEMM2 partial: acc2[dt] = C[d=32dt+row][m-tile mb], K = own 128 h ----
    f32x16 acc2[4];
#pragma unroll
    for (int i = 0; i < 16; i++) { acc2[0][i] = 0.f; acc2[1][i] = 0.f;
                                   acc2[2][i] = 0.f; acc2[3][i] = 0.f; }
#pragma unroll
    for (int kb = 0; kb < 8; kb++) {
      const f16* a2b = a2p + (kb << 4);
      half8_t ah[4], al[4];
#pragma unroll
      for (int dt = 0; dt < 4; dt++) {
        ah[dt] = *(const half8_t*)(a2b + dt * 8192);
        al[dt] = *(const half8_t*)(a2b + NW1 + dt * 8192);
      }
#pragma unroll
      for (int dt = 0; dt < 4; dt++) acc2[dt] = mfma_f16(ah[dt], bfh[kb], acc2[dt]);
#pragma unroll
      for (int dt = 0; dt < 4; dt++) acc2[dt] = mfma_f16(al[dt], bfh[kb], acc2[dt]);
#pragma unroll
      for (int dt = 0; dt < 4; dt++) acc2[dt] = mfma_f16(ah[dt], bfl[kb], acc2[dt]);
    }

    // ---- exchange partner-half partials via X, reduce, update Z ----
    // writer (mb,hh) writes tiles {2(1-hh), 2(1-hh)+1} into slot (mb, 1-hh).
    {
      float* Xs = Xbuf + (((mb << 1) | (1 - hh)) << 11);
#pragma unroll
      for (int ti = 0; ti < 2; ti++) {
        int dt = ((1 - hh) << 1) + ti;
#pragma unroll
        for (int reg = 0; reg < 16; reg++) {
          int row = (reg & 3) + ((reg >> 2) << 3) + (koct << 2);
          Xs[(ti << 10) + (row << 5) + col] = acc2[dt][reg];
        }
      }
    }
    __syncthreads();
    {
      const float* Xr = Xbuf + (((mb << 1) | hh) << 11);
      f16* zhr = Zh + (mrow << 7);
#pragma unroll
      for (int ti = 0; ti < 2; ti++) {
        int dt = (hh << 1) + ti;
        float sum[16];
#pragma unroll
        for (int reg = 0; reg < 16; reg++) {
          int row = (reg & 3) + ((reg >> 2) << 3) + (koct << 2);
          sum[reg] = acc2[dt][reg] + Xr[(ti << 10) + (row << 5) + col];
        }
#pragma unroll
        for (int qd = 0; qd < 4; qd++) {
          int d0 = (dt << 5) + (qd << 3) + (koct << 2);
          int c = (d0 + rot0) & 127;
          half4_t zh = *(half4_t*)(zhr + c);
          half4_t zl = *(half4_t*)(zhr + ZLO + c);
#pragma unroll
          for (int j = 0; j < 4; j++) {
            float zs = (float)zh[j] + (float)zl[j];
            zs += sum[(qd << 2) + j] * 0.00390625f;
            f16 h = (f16)zs; zh[j] = h; zl[j] = (f16)(zs - (float)h);
          }
          *(half4_t*)(zhr + c) = zh;
          *(half4_t*)(zhr + ZLO + c) = zl;
        }
      }
    }
    __syncthreads();
  }

  // ---- dist = ||rb - z||^2 over 64 rows (4 threads/row, 32 d each) ----
  float* pd = Xbuf;
  int* rwin = (int*)Xbuf + 64;
  {
    int row = tx >> 2, seg = tx & 3;
    int rotr = (row & 15) << 3;
    const f16* zhr = Zh + (row << 7);
    const float* rb = ws + WS_RB + b * 128 + (seg << 5);
    float s = 0.f;
#pragma unroll
    for (int o = 0; o < 4; o++) {
      int c = (((seg << 5) + (o << 3)) + rotr) & 127;
      half8_t zh = *(const half8_t*)(zhr + c);
      half8_t zl = *(const half8_t*)(zhr + ZLO + c);
      float4 r0 = *(const float4*)(rb + (o << 3));
      float4 r1 = *(const float4*)(rb + (o << 3) + 4);
      float rr[8] = {r0.x, r0.y, r0.z, r0.w, r1.x, r1.y, r1.z, r1.w};
#pragma unroll
      for (int j = 0; j < 8; j++) {
        float z = ((float)zh[j] + (float)zl[j]) * 0.00390625f;
        float dlt = rr[j] - z;
        s += dlt * dlt;
      }
    }
    s += __shfl_xor(s, 1);   // all 4 lanes of a row end bit-identical
    s += __shfl_xor(s, 2);
    if (seg == 0) pd[row] = s;
  }
  __syncthreads();
  if (tx < 64) {
    float v = pd[tx]; int idx = tx;
#pragma unroll
    for (int off = 32; off; off >>= 1) {
      float v2 = __shfl_xor(v, off);
      int   i2 = __shfl_xor(idx, off);
      if (v2 < v || (v2 == v && i2 < idx)) { v = v2; idx = i2; }
    }
    if (tx == 0) {
      ws[WS_BESTD + (b << 2) + t] = v;
      ((int*)ws)[WS_BESTI + (b << 2) + t] = k0 + idx;
      rwin[0] = idx;
    }
  }
  __syncthreads();
  if (tx < 32) {
    int rw = rwin[0];
    int c = ((tx << 2) + ((rw & 15) << 3)) & 127;
    half4_t zh = *(const half4_t*)(Zh + (rw << 7) + c);
    half4_t zl = *(const half4_t*)(Zh + ZLO + (rw << 7) + c);
    float4 z;
    z.x = ((float)zh[0] + (float)zl[0]) * 0.00390625f;
    z.y = ((float)zh[1] + (float)zl[1]) * 0.00390625f;
    z.z = ((float)zh[2] + (float)zl[2]) * 0.00390625f;
    z.w = ((float)zh[3] + (float)zl[3]) * 0.00390625f;
    *(float4*)(ws + WS_BESTZ + (((b << 2) + t) << 7) + (tx << 2)) = z;
  }
}

// ---------------- per-step update: pick tile winner, advance xhat ----------------
__global__ __launch_bounds__(128) void k_update(const float* __restrict__ x,
    float* __restrict__ ws, float* __restrict__ out, int m, int last)
{
  __shared__ int tsel;
  int tx = threadIdx.x, b = blockIdx.x;
  if (tx == 0) {
    float bv = ws[WS_BESTD + (b << 2)]; int bt = 0;
    for (int q = 1; q < 4; q++) {
      float v = ws[WS_BESTD + (b << 2) + q];
      if (v < bv) { bv = v; bt = q; }     // strict <: ties -> lowest k (tile order)
    }
    tsel = bt;
    int k = ((const int*)ws)[WS_BESTI + (b << 2) + bt];
    out[OUT_CODES + b * 8 + (m + 1)] = (float)k;
  }
  __syncthreads();
  int bt = tsel;
  float z  = ws[WS_BESTZ + (((b << 2) + bt) << 7) + tx];
  float xh = ws[WS_XHAT + b * 128 + tx] + z;
  ws[WS_XHAT + b * 128 + tx] = xh;
  ws[WS_RB   + b * 128 + tx] = x[b * 128 + tx] - xh;
  out[OUT_SIDE + (m + 1) * 131072 + b * 128 + tx] = xh;
  if (last) out[b * 128 + tx] = xh;       // final xhat == side[7]
}

extern "C" void kernel_launch(void* const* d_in, const int* in_sizes, int n_in,
                              void* d_out, int out_size, void* d_ws, size_t ws_size,
                              hipStream_t stream)
{
  const float* x   = (const float*)d_in[0];
  const float* cb0 = (const float*)d_in[1];
  const float* cbs = (const float*)d_in[2];
  const float* Wc  = (const float*)d_in[3];
  const float* bc  = (const float*)d_in[4];
  const float* W1  = (const float*)d_in[5];
  const float* W2  = (const float*)d_in[6];
  float* out = (float*)d_out;
  float* ws  = (float*)d_ws;
  f16* wsh = (f16*)(ws + WS_WSPLIT);

  k_wsplit<<<896, 256, 0, stream>>>(W1, W2, wsh);
  k_step0<<<1024, 256, 0, stream>>>(x, cb0, ws, out);
  for (int m = 0; m < 7; m++) {
    k_prep<<<1280, 128, 0, stream>>>(cbs + m * 256 * 128, Wc + m * 128 * 256,
                                     bc + m * 128, ws);
    k_step<<<4096, 256, 0, stream>>>(wsh, ws, m);
    k_update<<<1024, 128, 0, stream>>>(x, ws, out, m, (m == 6) ? 1 : 0);
  }
}

// Round 13
// 3690.127 us; speedup vs baseline: 1.2031x; 1.2031x over previous
//
#include <hip/hip_runtime.h>

// QINCo round 13: R10 + B-sharing via A-tile chains, A STREAMED (no preload
// arrays, no K-split) — the R11 idea with register demand held to ~130.
//  Wave (mb,hg): m-tile mb (B rows 32mb+col), tiles {2hg,2hg+1} of A:
//   GEMM1 h-tiles, GEMM2 d-tiles. Per kc: 2 LDS b128 (shared) + 4 global
//   b128 (streamed A hi/lo x 2 tiles) + 6 MFMA. LDS reads/layer/wave: 64
//   (R10: 128). acc1[2]+acc2[2] = 64 VGPR; no big arrays.
//  LDS: Zh|Zl|Hh|Hl [64][128] halfs (64KB), rotation-by-8 layout (R10).
//  Pre-split fp16 hi/lo weights (k_wsplit).
// Shapes: D=128, M=8, K=256, L=2, H=256, BS=1024.
// Out layout (floats): xhat[1024*128] | codes[1024*8] | side[8][1024*128]

typedef _Float16 f16;
typedef f16 half4_t __attribute__((ext_vector_type(4)));
typedef f16 half8_t __attribute__((ext_vector_type(8)));
typedef float f32x16 __attribute__((ext_vector_type(16)));

#define OUT_CODES 131072
#define OUT_SIDE  139264

// ws float offsets
#define WS_XHAT  0          // [1024][128]
#define WS_RB    131072     // [1024][128]  r = x - xhat
#define WS_Y     262144     // [1024][128]  y = xhat @ Wx^T
#define WS_ZC    393216     // [256][128]   zc = cb + cb@Wz^T + bc
#define WS_BESTD 425984     // [1024][4]
#define WS_BESTI 430080     // [1024][4] (int)
#define WS_BESTZ 434176     // [1024][4][128]
#define WS_WSPLIT 960000    // f16 region: W1H|W1L|W2H|W2L, NW1 halfs each
#define NW1 458752          // 7*2*256*128

#define HLO 8192            // hi->lo LDS offset (halfs), compile-time

__device__ __forceinline__ f32x16 mfma_f16(half8_t a, half8_t b, f32x16 c) {
  return __builtin_amdgcn_mfma_f32_32x32x16_f16(a, b, c, 0, 0, 0);
}

// ---------------- weight pre-split: fp32 -> scaled (x256) fp16 hi/lo ----------------
__global__ __launch_bounds__(256) void k_wsplit(const float* __restrict__ W1,
    const float* __restrict__ W2, f16* __restrict__ wsh)
{
  int i = (blockIdx.x * 256 + threadIdx.x) * 4;      // [0, 2*NW1)
  const float* src;
  f16* hi;
  if (i < NW1) { src = W1 + i; hi = wsh + i; }
  else         { src = W2 + (i - NW1); hi = wsh + 2 * NW1 + (i - NW1); }
  f16* lo = hi + NW1;
  float4 v = *(const float4*)src;
  half4_t h, l;
  float s;
  s = v.x * 256.f; h[0] = (f16)s; l[0] = (f16)(s - (float)h[0]);
  s = v.y * 256.f; h[1] = (f16)s; l[1] = (f16)(s - (float)h[1]);
  s = v.z * 256.f; h[2] = (f16)s; l[2] = (f16)(s - (float)h[2]);
  s = v.w * 256.f; h[3] = (f16)s; l[3] = (f16)(s - (float)h[3]);
  *(half4_t*)hi = h;
  *(half4_t*)lo = l;
}

// ---------------- step 0: nearest codebook0 row ----------------
__global__ __launch_bounds__(256) void k_step0(const float* __restrict__ x,
    const float* __restrict__ cb0, float* __restrict__ ws, float* __restrict__ out)
{
  __shared__ float xs[128];
  __shared__ float redv[4];
  __shared__ int   redi[4];
  __shared__ int   kwin;
  int tx = threadIdx.x, b = blockIdx.x;
  if (tx < 128) xs[tx] = x[b * 128 + tx];
  __syncthreads();
  const float* c = cb0 + tx * 128;   // k = tx
  float s = 0.f;
  for (int d = 0; d < 128; d += 4) {
    float4 cv = *(const float4*)(c + d);
    float4 xv = *(const float4*)(xs + d);
    float a0 = xv.x - cv.x, a1 = xv.y - cv.y, a2 = xv.z - cv.z, a3 = xv.w - cv.w;
    s += a0 * a0 + a1 * a1 + a2 * a2 + a3 * a3;
  }
  float v = s; int idx = tx;
  for (int off = 32; off; off >>= 1) {
    float v2 = __shfl_xor(v, off);
    int   i2 = __shfl_xor(idx, off);
    if (v2 < v || (v2 == v && i2 < idx)) { v = v2; idx = i2; }
  }
  if ((tx & 63) == 0) { redv[tx >> 6] = v; redi[tx >> 6] = idx; }
  __syncthreads();
  if (tx == 0) {
    float bv = redv[0]; int bi = redi[0];
    for (int w = 1; w < 4; w++)
      if (redv[w] < bv || (redv[w] == bv && redi[w] < bi)) { bv = redv[w]; bi = redi[w]; }
    kwin = bi;
    out[OUT_CODES + b * 8] = (float)bi;
  }
  __syncthreads();
  int k = kwin;
  if (tx < 128) {
    float xh = cb0[k * 128 + tx];
    ws[WS_XHAT + b * 128 + tx] = xh;
    ws[WS_RB   + b * 128 + tx] = xs[tx] - xh;
    out[OUT_SIDE + b * 128 + tx] = xh;   // side[0]
  }
}

// ---------------- per-step prep: zc and y (fp32) ----------------
__global__ __launch_bounds__(128) void k_prep(const float* __restrict__ cb,
    const float* __restrict__ Wc, const float* __restrict__ bcm, float* __restrict__ ws)
{
  __shared__ float row[128];
  int tx = threadIdx.x, blk = blockIdx.x;
  if (blk < 256) {          // zc[k][i] = cb[k][i] + sum_d cb[k][d]*Wc[i][d] + bc[i]
    row[tx] = cb[blk * 128 + tx];
    __syncthreads();
    const float* wrow = Wc + tx * 256;
    float s = 0.f;
    for (int d = 0; d < 128; d += 4) {
      float4 wv = *(const float4*)(wrow + d);
      float4 zv = *(const float4*)(row + d);
      s += wv.x * zv.x + wv.y * zv.y + wv.z * zv.z + wv.w * zv.w;
    }
    ws[WS_ZC + blk * 128 + tx] = row[tx] + s + bcm[tx];
  } else {                  // y[b][i] = sum_d xhat[b][d]*Wc[i][128+d]
    int b = blk - 256;
    row[tx] = ws[WS_XHAT + b * 128 + tx];
    __syncthreads();
    const float* wrow = Wc + tx * 256 + 128;
    float s = 0.f;
    for (int d = 0; d < 128; d += 4) {
      float4 wv = *(const float4*)(wrow + d);
      float4 zv = *(const float4*)(row + d);
      s += wv.x * zv.x + wv.y * zv.y + wv.z * zv.z + wv.w * zv.w;
    }
    ws[WS_Y + b * 128 + tx] = s;
  }
}

// ---------------- main step kernel ----------------
// 256 threads = 4 waves; wave w: mb = w&1, hg = w>>1.
// lane: col = lane&31, koct = lane>>5.
// LDS rows 128 halfs; logical d of row m at phys (d + 8*(m&15)) & 127.
// GEMM1 per hf: A = W1 h-tiles {2hg,2hg+1} of the hf's 128 (streamed),
//   B = Z rows 32mb+col (LDS, shared by both chains). C tiles -> H write.
// GEMM2 per hf: A = W2 d-tiles {2hg,2hg+1} (streamed), B = H rows 32mb+col.
//   acc2 accumulated across hf. C/D: col = m-in-tile, row = (reg&3)+8*(reg>>2)+4*koct.
__global__ __launch_bounds__(256, 2) void k_step(const f16* __restrict__ wsh,
    float* __restrict__ ws, int sm)
{
  __shared__ __align__(16) f16 lds[32768];     // 64 KB exactly
  f16* Zh = lds;            // [64][128]
  f16* Hh = lds + 2 * HLO;  // [64][128]; lo halves at +HLO from each
  int tx = threadIdx.x;
  int lane = tx & 63, w = tx >> 6;
  int col = lane & 31, koct = lane >> 5;
  int mb = w & 1, hg = w >> 1;
  int b = blockIdx.x >> 2, t = blockIdx.x & 3, k0 = t << 6;

  // ---- init Z = zc[k0+m] + y[b], split x256 into Zh/Zl (rotated store) ----
  {
    const float* zc = ws + WS_ZC + k0 * 128;
    const float* y  = ws + WS_Y + b * 128;
    for (int idx = tx; idx < 1024; idx += 256) {
      int m = idx & 63, d0 = (idx >> 6) << 3;
      float4 a  = *(const float4*)(zc + m * 128 + d0);
      float4 bb = *(const float4*)(zc + m * 128 + d0 + 4);
      float4 ya = *(const float4*)(y + d0);
      float4 yb = *(const float4*)(y + d0 + 4);
      float sv[8] = {a.x + ya.x, a.y + ya.y, a.z + ya.z, a.w + ya.w,
                     bb.x + yb.x, bb.y + yb.y, bb.z + yb.z, bb.w + yb.w};
      half8_t h8, l8;
#pragma unroll
      for (int j = 0; j < 8; j++) {
        float v = sv[j] * 256.f;
        f16 h = (f16)v; h8[j] = h; l8[j] = (f16)(v - (float)h);
      }
      int c0 = (d0 + ((m & 15) << 3)) & 127;
      *(half8_t*)(Zh + (m << 7) + c0) = h8;
      *(half8_t*)(Zh + HLO + (m << 7) + c0) = l8;
    }
  }
  __syncthreads();

  const int mrow = (mb << 5) + col;        // B row for both GEMMs
  const int rot0 = (col & 15) << 3;        // rotation for row mrow
  const f16* Zr = Zh + (mrow << 7);
  const f16* Hr = Hh + (mrow << 7);

  for (int l = 0; l < 2; l++) {
    const f16* w1h = wsh + (size_t)((sm * 2 + l) * 256) * 128;
    const f16* w2h = wsh + 2 * NW1 + (size_t)((sm * 2 + l) * 128) * 256;
    f32x16 acc2[2];
#pragma unroll
    for (int i = 0; i < 16; i++) { acc2[0][i] = 0.f; acc2[1][i] = 0.f; }

#pragma unroll
    for (int hf = 0; hf < 2; hf++) {
      // A bases: GEMM1 rows h = hf*128 + hg*64 + {0,32} + col
      const f16* a1p = w1h + (size_t)((hf << 7) + (hg << 6) + col) * 128 + (koct << 3);
      // GEMM2 rows d = hg*64 + {0,32} + col, k-base = hf*128
      const f16* a2p = w2h + (size_t)((hg << 6) + col) * 256 + (hf << 7) + (koct << 3);

      // ---- GEMM1: chains = 2 h-tiles, shared B reads, A streamed ----
      f32x16 acc1[2];
#pragma unroll
      for (int i = 0; i < 16; i++) { acc1[0][i] = 0.f; acc1[1][i] = 0.f; }
#pragma unroll
      for (int kc = 0; kc < 8; kc++) {
        int poff = (((kc << 4) + (koct << 3)) + rot0) & 127;
        half8_t bh = *(const half8_t*)(Zr + poff);
        half8_t bl = *(const half8_t*)(Zr + HLO + poff);
        const f16* a1b = a1p + (kc << 4);
        half8_t ah0 = *(const half8_t*)(a1b);
        half8_t ah1 = *(const half8_t*)(a1b + 32 * 128);
        half8_t al0 = *(const half8_t*)(a1b + NW1);
        half8_t al1 = *(const half8_t*)(a1b + NW1 + 32 * 128);
        acc1[0] = mfma_f16(ah0, bh, acc1[0]);
        acc1[1] = mfma_f16(ah1, bh, acc1[1]);
        acc1[0] = mfma_f16(al0, bh, acc1[0]);
        acc1[1] = mfma_f16(al1, bh, acc1[1]);
        acc1[0] = mfma_f16(ah0, bl, acc1[0]);
        acc1[1] = mfma_f16(ah1, bl, acc1[1]);
      }
      // epilogue1: relu, rescale (x 2^-8), split, store H[mrow][h_local]
#pragma unroll
      for (int ht = 0; ht < 2; ht++) {
#pragma unroll
        for (int qd = 0; qd < 4; qd++) {
          half4_t hv, lv;
#pragma unroll
          for (int j = 0; j < 4; j++) {
            float tv = fmaxf(acc1[ht][(qd << 2) + j], 0.f) * 0.00390625f;
            f16 h = (f16)tv; hv[j] = h; lv[j] = (f16)(tv - (float)h);
          }
          int c = (((hg << 6) + (ht << 5) + (qd << 3) + (koct << 2)) + rot0) & 127;
          *(half4_t*)(Hh + (mrow << 7) + c) = hv;
          *(half4_t*)(Hh + HLO + (mrow << 7) + c) = lv;
        }
      }
      __syncthreads();
      // ---- GEMM2 partial: chains = 2 d-tiles, shared B reads, A streamed ----
#pragma unroll
      for (int kc = 0; kc < 8; kc++) {
        int poff = (((kc << 4) + (koct << 3)) + rot0) & 127;
        half8_t bh = *(const half8_t*)(Hr + poff);
        half8_t bl = *(const half8_t*)(Hr + HLO + poff);
        const f16* a2b = a2p + (kc << 4);
        half8_t ah0 = *(const half8_t*)(a2b);
        half8_t ah1 = *(const half8_t*)(a2b + 32 * 256);
        half8_t al0 = *(const half8_t*)(a2b + NW1);
        half8_t al1 = *(const half8_t*)(a2b + NW1 + 32 * 256);
        acc2[0] = mfma_f16(ah0, bh, acc2[0]);
        acc2[1] = mfma_f16(ah1, bh, acc2[1]);
        acc2[0] = mfma_f16(al0, bh, acc2[0]);
        acc2[1] = mfma_f16(al1, bh, acc2[1]);
        acc2[0] = mfma_f16(ah0, bl, acc2[0]);
        acc2[1] = mfma_f16(ah1, bl, acc2[1]);
      }
      __syncthreads();
    }
    // ---- epilogue2: Z[mrow][d-tiles {2hg,2hg+1}] += acc2 * 2^-8 (scaled) ----
#pragma unroll
    for (int dt = 0; dt < 2; dt++) {
      f16* zhr = Zh + (mrow << 7);
#pragma unroll
      for (int qd = 0; qd < 4; qd++) {
        int c = (((hg << 6) + (dt << 5) + (qd << 3) + (koct << 2)) + rot0) & 127;
        half4_t zh = *(half4_t*)(zhr + c);
        half4_t zl = *(half4_t*)(zhr + HLO + c);
#pragma unroll
        for (int j = 0; j < 4; j++) {
          float zs = (float)zh[j] + (float)zl[j];
          zs += acc2[dt][(qd << 2) + j] * 0.00390625f;
          f16 h = (f16)zs; zh[j] = h; zl[j] = (f16)(zs - (float)h);
        }
        *(half4_t*)(zhr + c) = zh;
        *(half4_t*)(zhr + HLO + c) = zl;
      }
    }
    __syncthreads();
  }

  // ---- dist = ||rb - z||^2 over 64 rows (4 threads/row, 32 d each) ----
  float* pd = (float*)Hh;
  int* rwin = (int*)Hh + 64;
  {
    int row = tx >> 2, seg = tx & 3;
    int rotr = (row & 15) << 3;
    const f16* zhr = Zh + (row << 7);
    const float* rb = ws + WS_RB + b * 128 + (seg << 5);
    float s = 0.f;
#pragma unroll
    for (int o = 0; o < 4; o++) {
      int c = (((seg << 5) + (o << 3)) + rotr) & 127;
      half8_t zh = *(const half8_t*)(zhr + c);
      half8_t zl = *(const half8_t*)(zhr + HLO + c);
      float4 r0 = *(const float4*)(rb + (o << 3));
      float4 r1 = *(const float4*)(rb + (o << 3) + 4);
      float rr[8] = {r0.x, r0.y, r0.z, r0.w, r1.x, r1.y, r1.z, r1.w};
#pragma unroll
      for (int j = 0; j < 8; j++) {
        float z = ((float)zh[j] + (float)zl[j]) * 0.00390625f;
        float dlt = rr[j] - z;
        s += dlt * dlt;
      }
    }
    s += __shfl_xor(s, 1);   // all 4 lanes of a row end bit-identical
    s += __shfl_xor(s, 2);
    if (seg == 0) pd[row] = s;
  }
  __syncthreads();
  if (tx < 64) {
    float v = pd[tx]; int idx = tx;
#pragma unroll
    for (int off = 32; off; off >>= 1) {
      float v2 = __shfl_xor(v, off);
      int   i2 = __shfl_xor(idx, off);
      if (v2 < v || (v2 == v && i2 < idx)) { v = v2; idx = i2; }
    }
    if (tx == 0) {
      ws[WS_BESTD + (b << 2) + t] = v;
      ((int*)ws)[WS_BESTI + (b << 2) + t] = k0 + idx;
      rwin[0] = idx;
    }
  }
  __syncthreads();
  if (tx < 32) {
    int rw = rwin[0];
    int c = ((tx << 2) + ((rw & 15) << 3)) & 127;
    half4_t zh = *(const half4_t*)(Zh + (rw << 7) + c);
    half4_t zl = *(const half4_t*)(Zh + HLO + (rw << 7) + c);
    float4 z;
    z.x = ((float)zh[0] + (float)zl[0]) * 0.00390625f;
    z.y = ((float)zh[1] + (float)zl[1]) * 0.00390625f;
    z.z = ((float)zh[2] + (float)zl[2]) * 0.00390625f;
    z.w = ((float)zh[3] + (float)zl[3]) * 0.00390625f;
    *(float4*)(ws + WS_BESTZ + (((b << 2) + t) << 7) + (tx << 2)) = z;
  }
}

// ---------------- per-step update: pick tile winner, advance xhat ----------------
__global__ __launch_bounds__(128) void k_update(const float* __restrict__ x,
    float* __restrict__ ws, float* __restrict__ out, int m, int last)
{
  __shared__ int tsel;
  int tx = threadIdx.x, b = blockIdx.x;
  if (tx == 0) {
    float bv = ws[WS_BESTD + (b << 2)]; int bt = 0;
    for (int q = 1; q < 4; q++) {
      float v = ws[WS_BESTD + (b << 2) + q];
      if (v < bv) { bv = v; bt = q; }     // strict <: ties -> lowest k (tile order)
    }
    tsel = bt;
    int k = ((const int*)ws)[WS_BESTI + (b << 2) + bt];
    out[OUT_CODES + b * 8 + (m + 1)] = (float)k;
  }
  __syncthreads();
  int bt = tsel;
  float z  = ws[WS_BESTZ + (((b << 2) + bt) << 7) + tx];
  float xh = ws[WS_XHAT + b * 128 + tx] + z;
  ws[WS_XHAT + b * 128 + tx] = xh;
  ws[WS_RB   + b * 128 + tx] = x[b * 128 + tx] - xh;
  out[OUT_SIDE + (m + 1) * 131072 + b * 128 + tx] = xh;
  if (last) out[b * 128 + tx] = xh;       // final xhat == side[7]
}

extern "C" void kernel_launch(void* const* d_in, const int* in_sizes, int n_in,
                              void* d_out, int out_size, void* d_ws, size_t ws_size,
                              hipStream_t stream)
{
  const float* x   = (const float*)d_in[0];
  const float* cb0 = (const float*)d_in[1];
  const float* cbs = (const float*)d_in[2];
  const float* Wc  = (const float*)d_in[3];
  const float* bc  = (const float*)d_in[4];
  const float* W1  = (const float*)d_in[5];
  const float* W2  = (const float*)d_in[6];
  float* out = (float*)d_out;
  float* ws  = (float*)d_ws;
  f16* wsh = (f16*)(ws + WS_WSPLIT);

  k_wsplit<<<896, 256, 0, stream>>>(W1, W2, wsh);
  k_step0<<<1024, 256, 0, stream>>>(x, cb0, ws, out);
  for (int m = 0; m < 7; m++) {
    k_prep<<<1280, 128, 0, stream>>>(cbs + m * 256 * 128, Wc + m * 128 * 256,
                                     bc + m * 128, ws);
    k_step<<<4096, 256, 0, stream>>>(wsh, ws, m);
    k_update<<<1024, 128, 0, stream>>>(x, ws, out, m, (m == 6) ? 1 : 0);
  }
}